// Round 16
// baseline (243.108 us; speedup 1.0000x reference)
//
#include <hip/hip_runtime.h>
#include <math.h>

#define NP 16384
#define NR 8192

typedef __attribute__((ext_vector_type(8))) short short8;
typedef __attribute__((ext_vector_type(4))) float f32x4;

__device__ inline unsigned short f2b(float f) {
  unsigned int x = __float_as_uint(f);
  return (unsigned short)((x + 0x7FFFu + ((x >> 16) & 1u)) >> 16);  // RNE
}
__device__ inline float blo(unsigned int u) { return __uint_as_float(u << 16); }
__device__ inline float bhi(unsigned int u) { return __uint_as_float(u & 0xffff0000u); }

// ---------------- fused preprocessing (unchanged, R11-R15-verified)
__global__ __launch_bounds__(256) void k_pre(const float* __restrict__ rf,
                                             const float* __restrict__ rxyz,
                                             const float* __restrict__ pf,
                                             const float* __restrict__ s0, const float* __restrict__ s1,
                                             const float* __restrict__ s2, const float* __restrict__ s3,
                                             const float* __restrict__ s4, const float* __restrict__ s5,
                                             const float* __restrict__ s6, const float* __restrict__ s7,
                                             unsigned short* __restrict__ rgbTb,
                                             float4* __restrict__ rxyz4,
                                             unsigned short* __restrict__ fullp,
                                             unsigned short* __restrict__ dst) {
  __shared__ float tile[128][65];
  int b = blockIdx.x, t = threadIdx.x;
  if (b < 128) {
    int r0 = b * 64;
    for (int e = 0; e < 32; ++e) {
      int idx = t + e * 256;
      int c = idx >> 6, rl = idx & 63;
      tile[c][rl] = rf[c * NR + r0 + rl];
    }
    __syncthreads();
    for (int e = 0; e < 32; ++e) {
      int idx = t + e * 256;
      int rl = idx >> 7, c = idx & 127;
      rgbTb[(size_t)(r0 + rl) * 128 + c] = f2b(tile[c][rl]);
    }
    if (b == 0 && t < 128) rgbTb[(size_t)NR * 128 + t] = 0;
    if ((t >> 6) == 0) {
      int i = r0 + (t & 63);
      float x = rxyz[i * 3], y = rxyz[i * 3 + 1], z = rxyz[i * 3 + 2];
      rxyz4[i] = make_float4(x, y, z, fmaf(x, x, fmaf(y, y, z * z)));
    }
  } else if (b < 384) {
    int n0 = (b - 128) * 64;
    for (int e = 0; e < 8; ++e) {
      int idx = t + e * 256;
      int c = idx >> 6, nl = idx & 63;
      tile[c][nl] = pf[c * NP + n0 + nl];
    }
    __syncthreads();
    for (int e = 0; e < 8; ++e) {
      int idx = t + e * 256;
      int nl = idx >> 5, c = idx & 31;
      fullp[(size_t)(n0 + nl) * 32 + c] = f2b(tile[c][nl]);
    }
  } else {
    const int sizes[8] = {147456, 49152, 65536, 32768, 25600, 25600, 20480, 16384};
    const int offs[8]  = {0, 147456, 196608, 262144, 294912, 320512, 346112, 366592};
    const float* srcs[8] = {s0, s1, s2, s3, s4, s5, s6, s7};
    int j = b - 384;
    int m = j / 72, bx = j % 72;
    int i = (bx * 256 + t) * 8;
    if (i >= sizes[m]) return;
    const float4* sp = (const float4*)(srcs[m] + i);
    float4 a = sp[0], c = sp[1];
    uint4 o;
    o.x = f2b(a.x) | ((unsigned int)f2b(a.y) << 16);
    o.y = f2b(a.z) | ((unsigned int)f2b(a.w) << 16);
    o.z = f2b(c.x) | ((unsigned int)f2b(c.y) << 16);
    o.w = f2b(c.z) | ((unsigned int)f2b(c.w) << 16);
    *(uint4*)(dst + offs[m] + i) = o;
  }
}

// ---------------- three_nn partials, 4 points/lane (unchanged, R10-R15-verified)
__global__ __launch_bounds__(256) void k_nn_part(const float* __restrict__ pxyz,
                                                 const float4* __restrict__ rxyz4,
                                                 float* __restrict__ pd,
                                                 int* __restrict__ pi) {
  __shared__ float4 pts[512];
  __shared__ float msd[4][3][256];
  __shared__ int   mid[4][3][256];
  int t = threadIdx.x;
  int g = blockIdx.x, s = blockIdx.y;
  int lane = t & 63, w = t >> 6;
  int rbase = s * 512;
#pragma unroll
  for (int e = 0; e < 2; ++e) pts[t + e * 256] = rxyz4[rbase + t + e * 256];
  const float R2L = 0.005626125f;
  const float MARGIN = 4e-6f;
  float nx2[4], ny2[4], nz2[4], pp[4], thr[4];
  float s0[4], s1[4], s2[4];
  int i0[4], i1[4], i2[4];
#pragma unroll
  for (int j = 0; j < 4; ++j) {
    int n = g * 256 + j * 64 + lane;
    float px = pxyz[n * 3], py = pxyz[n * 3 + 1], pz = pxyz[n * 3 + 2];
    pp[j] = fmaf(px, px, fmaf(py, py, pz * pz));
    nx2[j] = -2.f * px; ny2[j] = -2.f * py; nz2[j] = -2.f * pz;
    s0[j] = R2L; s1[j] = R2L; s2[j] = R2L;
    i0[j] = 0; i1[j] = 0; i2[j] = 0;
    thr[j] = R2L + MARGIN - pp[j];
  }
  __syncthreads();
  int base = w * 128;
#pragma unroll 4
  for (int loc = 0; loc < 128; ++loc) {
    float4 r = pts[base + loc];
    int idx = rbase + base + loc;
#pragma unroll
    for (int j = 0; j < 4; ++j) {
      float e3 = fmaf(nz2[j], r.z, fmaf(ny2[j], r.y, fmaf(nx2[j], r.x, r.w)));
      if (__ballot(e3 < thr[j])) {
        float dx = fmaf(0.5f, nx2[j], r.x);
        float dy = fmaf(0.5f, ny2[j], r.y);
        float dz = fmaf(0.5f, nz2[j], r.z);
        float d2 = fmaf(dx, dx, fmaf(dy, dy, dz * dz));
        if (d2 < s2[j]) {
          if (d2 < s1[j]) {
            s2[j] = s1[j]; i2[j] = i1[j];
            if (d2 < s0[j]) { s1[j] = s0[j]; i1[j] = i0[j]; s0[j] = d2; i0[j] = idx; }
            else            { s1[j] = d2; i1[j] = idx; }
          } else { s2[j] = d2; i2[j] = idx; }
        }
        thr[j] = s2[j] + MARGIN - pp[j];
      }
    }
  }
#pragma unroll
  for (int j = 0; j < 4; ++j) {
    int pl = j * 64 + lane;
    msd[w][0][pl] = s0[j]; msd[w][1][pl] = s1[j]; msd[w][2][pl] = s2[j];
    mid[w][0][pl] = i0[j]; mid[w][1][pl] = i1[j]; mid[w][2][pl] = i2[j];
  }
  __syncthreads();
  {
    float a0 = msd[0][0][t], a1 = msd[0][1][t], a2 = msd[0][2][t];
    int b0 = mid[0][0][t], b1 = mid[0][1][t], b2 = mid[0][2][t];
    for (int ww = 1; ww < 4; ++ww) {
      for (int q = 0; q < 3; ++q) {
        float d2 = msd[ww][q][t]; int i = mid[ww][q][t];
        if (d2 < a2) {
          if (d2 < a1) {
            a2 = a1; b2 = b1;
            if (d2 < a0) { a1 = a0; b1 = b0; a0 = d2; b0 = i; }
            else         { a1 = d2; b1 = i; }
          } else { a2 = d2; b2 = i; }
        }
      }
    }
    int off = ((g * 16 + s) * 256 + t) * 3;
    pd[off + 0] = a0; pd[off + 1] = a1; pd[off + 2] = a2;
    pi[off + 0] = b0; pi[off + 1] = b1; pi[off + 2] = b2;
  }
}

// ---------------- fused-MLP layer, 16-row blocks: 8-way o-split, single row-tile.
// wo in [0,8) via &7 so guards fold except dh1/dh2 tile 1. af from global (L2-hot).
template <int C, int O, int COFF, bool BN, bool RELU>
__device__ __forceinline__ void mlp_layer(const unsigned short* __restrict__ W,
                                          const float* __restrict__ bias,
                                          const float* __restrict__ bnp,
                                          const unsigned short* Xs,
                                          unsigned short* Ys,
                                          int wo, int q, int l15) {
  constexpr int NC = C / 32;
  constexpr int NT = O / 16;
  constexpr int MT = (NT + 7) / 8;
  f32x4 acc[MT];
  short8 afb[2][MT];
  const unsigned short* wp[MT];
#pragma unroll
  for (int i = 0; i < MT; ++i) {
    acc[i] = (f32x4){0.f, 0.f, 0.f, 0.f};
    int ot = wo + i * 8;
    wp[i] = W + (size_t)(((ot < NT) ? ot : 0) * 16 + l15) * C + q * 8;
  }
#pragma unroll
  for (int k = 0; k < 2 && k < NC; ++k)
#pragma unroll
    for (int i = 0; i < MT; ++i)
      if (wo + i * 8 < NT) afb[k][i] = *(const short8*)(wp[i] + k * 32);
  short8 bf0 = *(const short8*)&Xs[l15 * 392 + q * 8];
#pragma unroll
  for (int k = 0; k < NC; ++k) {
    short8 nbf0 = bf0;
    if (k + 1 < NC)                   // compile-time
      nbf0 = *(const short8*)&Xs[l15 * 392 + (k + 1) * 32 + q * 8];
    int slot = k & 1;
#pragma unroll
    for (int i = 0; i < MT; ++i) {
      if (wo + i * 8 < NT)            // folds for all layers but dh1/dh2 i=1
        acc[i] = __builtin_amdgcn_mfma_f32_16x16x32_bf16(afb[slot][i], bf0, acc[i], 0, 0, 0);
    }
    if (k + 2 < NC) {                 // compile-time
#pragma unroll
      for (int i = 0; i < MT; ++i)
        if (wo + i * 8 < NT) afb[slot][i] = *(const short8*)(wp[i] + (k + 2) * 32);
    }
    bf0 = nbf0;
  }
#pragma unroll
  for (int i = 0; i < MT; ++i) {
    int ot = wo + i * 8;
    if (ot >= NT) continue;
    int o4 = ot * 16 + q * 4;
    f32x4 bb = *(const f32x4*)(bias + o4);
    f32x4 sc, sh;
    if (BN) {
      f32x4 g  = *(const f32x4*)(bnp + o4);
      f32x4 be = *(const f32x4*)(bnp + O + o4);
      f32x4 mm = *(const f32x4*)(bnp + 2 * O + o4);
      f32x4 vv = *(const f32x4*)(bnp + 3 * O + o4);
#pragma unroll
      for (int r = 0; r < 4; ++r) {
        float inv = g[r] * rsqrtf(vv[r] + 1e-5f);
        sc[r] = inv; sh[r] = (bb[r] - mm[r]) * inv + be[r];
      }
    } else {
      sc = (f32x4){1.f, 1.f, 1.f, 1.f}; sh = bb;
    }
    ushort4 u;
#pragma unroll
    for (int r = 0; r < 4; ++r) {
      float x = acc[i][r] * sc[r] + sh[r];
      if (RELU) x = fmaxf(x, 0.f);
      ((unsigned short*)&u)[r] = f2b(x);
    }
    *(ushort4*)&Ys[l15 * 392 + COFF + ot * 16 + q * 4] = u;
  }
}

// ---------------- one-kernel MLP: 16 points/block, 1024 blocks -> 4 blocks/CU
// (32 waves/CU, HW max) for latency hiding; LDS 24.5 KB/block.
__global__ __launch_bounds__(512) void k_mlp(
    const unsigned short* __restrict__ rgbTb,
    const float* __restrict__ pd, const int* __restrict__ pi,
    const unsigned short* __restrict__ fullp,
    const unsigned short* __restrict__ wcc1, const unsigned short* __restrict__ wcc2,
    const unsigned short* __restrict__ wco1, const unsigned short* __restrict__ wco2,
    const unsigned short* __restrict__ wdh1, const unsigned short* __restrict__ wdh2,
    const unsigned short* __restrict__ wdh3, const unsigned short* __restrict__ wsh1,
    const float* __restrict__ cc1_b, const float* __restrict__ cc_bn,
    const float* __restrict__ cc2_b,
    const float* __restrict__ co1_b, const float* __restrict__ co_bn,
    const float* __restrict__ co2_b,
    const float* __restrict__ dh1_b, const float* __restrict__ dh1_bn,
    const float* __restrict__ dh2_b, const float* __restrict__ dh2_bn,
    const float* __restrict__ dh3_b,
    const float* __restrict__ sh1_b, const float* __restrict__ sh_bn,
    const float* __restrict__ sh2_w, const float* __restrict__ sh2_b,
    const float* __restrict__ pxyz, float* __restrict__ out) {
  __shared__ unsigned short Ab[16 * 392];   // 12.25 KB
  __shared__ unsigned short Bb[16 * 392];   // 12.25 KB
  int t = threadIdx.x, lane = t & 63, w = t >> 6;
  int wo = w & 7;                           // range [0,8) for guard folding
  int q = lane >> 4, l15 = lane & 15;
  int n0 = blockIdx.x * 16;
  const float R2 = 0.075f * 0.075f;
  unsigned int mreg[2];                     // maxf in registers (2 rows/wave)
  // ---- merge (48-key lexicographic wave-min, verified) + gather + maxf
#pragma unroll
  for (int pj = 0; pj < 2; ++pj) {
    int r = w * 2 + pj;
    int n = n0 + r;
    int g = n >> 8, l = n & 255;
    unsigned long long key = ~0ull;
    if (lane < 48) {
      int s = lane / 3, qq = lane % 3;
      int off = ((g * 16 + s) * 256 + l) * 3 + qq;
      key = ((unsigned long long)__float_as_uint(pd[off]) << 32) | (unsigned int)pi[off];
    }
    unsigned long long mk[3];
#pragma unroll
    for (int rr = 0; rr < 3; ++rr) {
      unsigned long long m = key;
#pragma unroll
      for (int o = 1; o < 64; o <<= 1) {
        unsigned long long other = __shfl_xor(m, o);
        m = other < m ? other : m;
      }
      mk[rr] = m;
      if (key == m) key = ~0ull;
    }
    float d0 = __uint_as_float((unsigned int)(mk[0] >> 32));
    float d1 = __uint_as_float((unsigned int)(mk[1] >> 32));
    float d2 = __uint_as_float((unsigned int)(mk[2] >> 32));
    int j0 = (d0 > R2) ? NR : (int)(mk[0] & 0xffffffffu);
    int j1 = (d1 > R2) ? NR : (int)(mk[1] & 0xffffffffu);
    int j2 = (d2 > R2) ? NR : (int)(mk[2] & 0xffffffffu);
    unsigned int a = ((const unsigned int*)(rgbTb + (size_t)j0 * 128))[lane];
    unsigned int b = ((const unsigned int*)(rgbTb + (size_t)j1 * 128))[lane];
    unsigned int c = ((const unsigned int*)(rgbTb + (size_t)j2 * 128))[lane];
    unsigned int* xr = (unsigned int*)&Ab[r * 392];
    xr[lane] = a; xr[64 + lane] = b; xr[128 + lane] = c;
    float ml = fmaxf(blo(a), fmaxf(blo(b), blo(c)));
    float mh = fmaxf(bhi(a), fmaxf(bhi(b), bhi(c)));
    mreg[pj] = (__float_as_uint(mh) & 0xffff0000u) | (__float_as_uint(ml) >> 16);
  }
  __syncthreads();
  mlp_layer<384, 384, 0, true,  true >(wcc1, cc1_b, cc_bn, Ab, Bb, wo, q, l15);
  __syncthreads();
  // cc2 writes Ab cols 0..127; maxf (registers) -> Ab cols 128..255 — disjoint.
#pragma unroll
  for (int pj = 0; pj < 2; ++pj)
    ((unsigned int*)&Ab[(w * 2 + pj) * 392])[64 + lane] = mreg[pj];
  mlp_layer<384, 128, 0, false, false>(wcc2, cc2_b, nullptr, Bb, Ab, wo, q, l15);
  __syncthreads();
  mlp_layer<256, 256, 0, true,  true >(wco1, co1_b, co_bn, Ab, Bb, wo, q, l15);
  __syncthreads();
  mlp_layer<256, 128, 32, false, false>(wco2, co2_b, nullptr, Bb, Ab, wo, q, l15);
  for (int idx = t; idx < 64; idx += 512) {     // pcd feats -> Ab cols 0..31
    int row = idx >> 2, c8 = idx & 3;
    *(uint4*)&Ab[row * 392 + c8 * 8] = *(const uint4*)(fullp + (size_t)(n0 + row) * 32 + c8 * 8);
  }
  __syncthreads();
  mlp_layer<160, 160, 0, true,  true >(wdh1, dh1_b, dh1_bn, Ab, Bb, wo, q, l15);
  __syncthreads();
  mlp_layer<160, 160, 0, true,  true >(wdh2, dh2_b, dh2_bn, Bb, Ab, wo, q, l15);
  __syncthreads();
  mlp_layer<160, 128, 0, false, false>(wdh3, dh3_b, nullptr, Ab, Bb, wo, q, l15); // fp -> Bb
  __syncthreads();
  mlp_layer<128, 128, 0, true,  true >(wsh1, sh1_b, sh_bn, Bb, Ab, wo, q, l15);   // s  -> Ab
  __syncthreads();
  // ---- tail: 2 rows/wave (row = w*2 + lane>>5), 32 lanes per row, 4 cols/lane
  int c4 = (lane & 31) * 4;
  int row = w * 2 + (lane >> 5);
  float4 w0 = *(const float4*)(sh2_w + c4);
  float bvv = sh2_b[0];
  uint2 raw = *(const uint2*)&Ab[row * 392 + c4];
  float acc = blo(raw.x) * w0.x + bhi(raw.x) * w0.y + blo(raw.y) * w0.z + bhi(raw.y) * w0.w;
  acc += __shfl_xor(acc, 1); acc += __shfl_xor(acc, 2);
  acc += __shfl_xor(acc, 4); acc += __shfl_xor(acc, 8); acc += __shfl_xor(acc, 16);
  if ((lane & 31) == 0) out[49152 + n0 + row] = 1.f / (1.f + expf(-(acc + bvv)));
  uint2 rf = *(const uint2*)&Bb[row * 392 + c4];
  float v[4] = {blo(rf.x), bhi(rf.x), blo(rf.y), bhi(rf.y)};
  float s = 0.f;
#pragma unroll
  for (int i = 0; i < 4; ++i) s = fmaf(v[i], v[i], s);
  s += __shfl_xor(s, 1); s += __shfl_xor(s, 2);
  s += __shfl_xor(s, 4); s += __shfl_xor(s, 8); s += __shfl_xor(s, 16);
  float inv = 1.f / fmaxf(sqrtf(s), 1e-12f);
  *(float4*)(out + 65536 + (size_t)(n0 + row) * 128 + c4) =
      make_float4(v[0] * inv, v[1] * inv, v[2] * inv, v[3] * inv);
  for (int i = t; i < 48; i += 512) out[n0 * 3 + i] = pxyz[n0 * 3 + i];
}

extern "C" void kernel_launch(void* const* d_in, const int* in_sizes, int n_in,
                              void* d_out, int out_size, void* d_ws, size_t ws_size,
                              hipStream_t stream) {
  const float* pcd_xyz = (const float*)d_in[0];
  const float* rgb_xyz = (const float*)d_in[1];
  const float* pcd_f   = (const float*)d_in[2];
  const float* rgb_f   = (const float*)d_in[3];
  const float* cc1_w = (const float*)d_in[4];  const float* cc1_b = (const float*)d_in[5];
  const float* cc_bn = (const float*)d_in[6];
  const float* cc2_w = (const float*)d_in[7];  const float* cc2_b = (const float*)d_in[8];
  const float* co1_w = (const float*)d_in[9];  const float* co1_b = (const float*)d_in[10];
  const float* co_bn = (const float*)d_in[11];
  const float* co2_w = (const float*)d_in[12]; const float* co2_b = (const float*)d_in[13];
  const float* dh1_w = (const float*)d_in[14]; const float* dh1_b = (const float*)d_in[15];
  const float* dh1_bn = (const float*)d_in[16];
  const float* dh2_w = (const float*)d_in[17]; const float* dh2_b = (const float*)d_in[18];
  const float* dh2_bn = (const float*)d_in[19];
  const float* dh3_w = (const float*)d_in[20]; const float* dh3_b = (const float*)d_in[21];
  const float* sh1_w = (const float*)d_in[22]; const float* sh1_b = (const float*)d_in[23];
  const float* sh_bn = (const float*)d_in[24];
  const float* sh2_w = (const float*)d_in[25]; const float* sh2_b = (const float*)d_in[26];

  char* ws = (char*)d_ws;
  float* out = (float*)d_out;

  unsigned short* wb    = (unsigned short*)(ws);              // 766 KB
  unsigned short* rgbTb = (unsigned short*)(ws + 0x100000);   // 2.1 MB
  float4* rxyz4         = (float4*)(ws + 0x320000);           // 128 KB
  float* pd  = (float*)(ws + 0x400000);                       // 3 MB
  int*   pi  = (int*)(ws + 0x700000);                         // 3 MB
  unsigned short* fullp = (unsigned short*)(ws + 0xA00000);   // (NP,32) bf16 = 1 MB

  unsigned short* wb_cc1 = wb;
  unsigned short* wb_cc2 = wb + 147456;
  unsigned short* wb_co1 = wb + 196608;
  unsigned short* wb_co2 = wb + 262144;
  unsigned short* wb_dh1 = wb + 294912;
  unsigned short* wb_dh2 = wb + 320512;
  unsigned short* wb_dh3 = wb + 346112;
  unsigned short* wb_sh1 = wb + 366592;

  k_pre<<<960, 256, 0, stream>>>(rgb_f, rgb_xyz, pcd_f,
                                 cc1_w, cc2_w, co1_w, co2_w, dh1_w, dh2_w, dh3_w, sh1_w,
                                 rgbTb, rxyz4, fullp, wb);
  k_nn_part<<<dim3(64, 16), 256, 0, stream>>>(pcd_xyz, rxyz4, pd, pi);
  k_mlp<<<1024, 512, 0, stream>>>(rgbTb, pd, pi, fullp,
                                  wb_cc1, wb_cc2, wb_co1, wb_co2,
                                  wb_dh1, wb_dh2, wb_dh3, wb_sh1,
                                  cc1_b, cc_bn, cc2_b, co1_b, co_bn, co2_b,
                                  dh1_b, dh1_bn, dh2_b, dh2_bn, dh3_b,
                                  sh1_b, sh_bn, sh2_w, sh2_b,
                                  pcd_xyz, out);
}

// Round 17
// 185.185 us; speedup vs baseline: 1.3128x; 1.3128x over previous
//
#include <hip/hip_runtime.h>
#include <math.h>

#define NP 16384
#define NR 8192

typedef __attribute__((ext_vector_type(8))) short short8;
typedef __attribute__((ext_vector_type(4))) float f32x4;

__device__ inline unsigned short f2b(float f) {
  unsigned int x = __float_as_uint(f);
  return (unsigned short)((x + 0x7FFFu + ((x >> 16) & 1u)) >> 16);  // RNE
}
__device__ inline float blo(unsigned int u) { return __uint_as_float(u << 16); }
__device__ inline float bhi(unsigned int u) { return __uint_as_float(u & 0xffff0000u); }

// ---------------- fused preprocessing. Weight conversion now REPACKS TILE-MAJOR:
// dst group g = (ot*NC + k)*64 + lane holds W[o=ot*16+(lane&15)][c=k*32+(lane>>4)*8 ..+7]
// so an MFMA A-fragment load is ONE coalesced 1 KB wave transaction (was 16x64B).
__global__ __launch_bounds__(256) void k_pre(const float* __restrict__ rf,
                                             const float* __restrict__ rxyz,
                                             const float* __restrict__ pf,
                                             const float* __restrict__ s0, const float* __restrict__ s1,
                                             const float* __restrict__ s2, const float* __restrict__ s3,
                                             const float* __restrict__ s4, const float* __restrict__ s5,
                                             const float* __restrict__ s6, const float* __restrict__ s7,
                                             unsigned short* __restrict__ rgbTb,
                                             float4* __restrict__ rxyz4,
                                             unsigned short* __restrict__ fullp,
                                             unsigned short* __restrict__ dst) {
  __shared__ float tile[128][65];
  int b = blockIdx.x, t = threadIdx.x;
  if (b < 128) {
    int r0 = b * 64;
    for (int e = 0; e < 32; ++e) {
      int idx = t + e * 256;
      int c = idx >> 6, rl = idx & 63;
      tile[c][rl] = rf[c * NR + r0 + rl];
    }
    __syncthreads();
    for (int e = 0; e < 32; ++e) {
      int idx = t + e * 256;
      int rl = idx >> 7, c = idx & 127;
      rgbTb[(size_t)(r0 + rl) * 128 + c] = f2b(tile[c][rl]);
    }
    if (b == 0 && t < 128) rgbTb[(size_t)NR * 128 + t] = 0;
    if ((t >> 6) == 0) {
      int i = r0 + (t & 63);
      float x = rxyz[i * 3], y = rxyz[i * 3 + 1], z = rxyz[i * 3 + 2];
      rxyz4[i] = make_float4(x, y, z, fmaf(x, x, fmaf(y, y, z * z)));
    }
  } else if (b < 384) {
    int n0 = (b - 128) * 64;
    for (int e = 0; e < 8; ++e) {
      int idx = t + e * 256;
      int c = idx >> 6, nl = idx & 63;
      tile[c][nl] = pf[c * NP + n0 + nl];
    }
    __syncthreads();
    for (int e = 0; e < 8; ++e) {
      int idx = t + e * 256;
      int nl = idx >> 5, c = idx & 31;
      fullp[(size_t)(n0 + nl) * 32 + c] = f2b(tile[c][nl]);
    }
  } else {
    const int groups[8] = {18432, 6144, 8192, 4096, 3200, 3200, 2560, 2048}; // short8 groups
    const int Cs[8]     = {384, 384, 256, 256, 160, 160, 160, 128};
    const int offs[8]   = {0, 147456, 196608, 262144, 294912, 320512, 346112, 366592};
    const float* srcs[8] = {s0, s1, s2, s3, s4, s5, s6, s7};
    int j = b - 384;
    int m = j / 72, bx = j % 72;
    int gidx = bx * 256 + t;
    if (gidx >= groups[m]) return;
    int C = Cs[m], NC = C >> 5;
    int ot = gidx / (NC * 64);
    int rem = gidx - ot * (NC * 64);
    int k = rem >> 6, lane = rem & 63;
    int q = lane >> 4, l15 = lane & 15;
    const float* sp = srcs[m] + (size_t)(ot * 16 + l15) * C + k * 32 + q * 8;
    float4 a = *(const float4*)sp, c4 = *(const float4*)(sp + 4);
    uint4 o;
    o.x = f2b(a.x) | ((unsigned int)f2b(a.y) << 16);
    o.y = f2b(a.z) | ((unsigned int)f2b(a.w) << 16);
    o.z = f2b(c4.x) | ((unsigned int)f2b(c4.y) << 16);
    o.w = f2b(c4.z) | ((unsigned int)f2b(c4.w) << 16);
    *(uint4*)(dst + offs[m] + (size_t)gidx * 8) = o;
  }
}

// ---------------- three_nn partials, 4 points/lane (unchanged, R10-R16-verified)
__global__ __launch_bounds__(256) void k_nn_part(const float* __restrict__ pxyz,
                                                 const float4* __restrict__ rxyz4,
                                                 float* __restrict__ pd,
                                                 int* __restrict__ pi) {
  __shared__ float4 pts[512];
  __shared__ float msd[4][3][256];
  __shared__ int   mid[4][3][256];
  int t = threadIdx.x;
  int g = blockIdx.x, s = blockIdx.y;
  int lane = t & 63, w = t >> 6;
  int rbase = s * 512;
#pragma unroll
  for (int e = 0; e < 2; ++e) pts[t + e * 256] = rxyz4[rbase + t + e * 256];
  const float R2L = 0.005626125f;
  const float MARGIN = 4e-6f;
  float nx2[4], ny2[4], nz2[4], pp[4], thr[4];
  float s0[4], s1[4], s2[4];
  int i0[4], i1[4], i2[4];
#pragma unroll
  for (int j = 0; j < 4; ++j) {
    int n = g * 256 + j * 64 + lane;
    float px = pxyz[n * 3], py = pxyz[n * 3 + 1], pz = pxyz[n * 3 + 2];
    pp[j] = fmaf(px, px, fmaf(py, py, pz * pz));
    nx2[j] = -2.f * px; ny2[j] = -2.f * py; nz2[j] = -2.f * pz;
    s0[j] = R2L; s1[j] = R2L; s2[j] = R2L;
    i0[j] = 0; i1[j] = 0; i2[j] = 0;
    thr[j] = R2L + MARGIN - pp[j];
  }
  __syncthreads();
  int base = w * 128;
#pragma unroll 4
  for (int loc = 0; loc < 128; ++loc) {
    float4 r = pts[base + loc];
    int idx = rbase + base + loc;
#pragma unroll
    for (int j = 0; j < 4; ++j) {
      float e3 = fmaf(nz2[j], r.z, fmaf(ny2[j], r.y, fmaf(nx2[j], r.x, r.w)));
      if (__ballot(e3 < thr[j])) {
        float dx = fmaf(0.5f, nx2[j], r.x);
        float dy = fmaf(0.5f, ny2[j], r.y);
        float dz = fmaf(0.5f, nz2[j], r.z);
        float d2 = fmaf(dx, dx, fmaf(dy, dy, dz * dz));
        if (d2 < s2[j]) {
          if (d2 < s1[j]) {
            s2[j] = s1[j]; i2[j] = i1[j];
            if (d2 < s0[j]) { s1[j] = s0[j]; i1[j] = i0[j]; s0[j] = d2; i0[j] = idx; }
            else            { s1[j] = d2; i1[j] = idx; }
          } else { s2[j] = d2; i2[j] = idx; }
        }
        thr[j] = s2[j] + MARGIN - pp[j];
      }
    }
  }
#pragma unroll
  for (int j = 0; j < 4; ++j) {
    int pl = j * 64 + lane;
    msd[w][0][pl] = s0[j]; msd[w][1][pl] = s1[j]; msd[w][2][pl] = s2[j];
    mid[w][0][pl] = i0[j]; mid[w][1][pl] = i1[j]; mid[w][2][pl] = i2[j];
  }
  __syncthreads();
  {
    float a0 = msd[0][0][t], a1 = msd[0][1][t], a2 = msd[0][2][t];
    int b0 = mid[0][0][t], b1 = mid[0][1][t], b2 = mid[0][2][t];
    for (int ww = 1; ww < 4; ++ww) {
      for (int q = 0; q < 3; ++q) {
        float d2 = msd[ww][q][t]; int i = mid[ww][q][t];
        if (d2 < a2) {
          if (d2 < a1) {
            a2 = a1; b2 = b1;
            if (d2 < a0) { a1 = a0; b1 = b0; a0 = d2; b0 = i; }
            else         { a1 = d2; b1 = i; }
          } else { a2 = d2; b2 = i; }
        }
      }
    }
    int off = ((g * 16 + s) * 256 + t) * 3;
    pd[off + 0] = a0; pd[off + 1] = a1; pd[off + 2] = a2;
    pi[off + 0] = b0; pi[off + 1] = b1; pi[off + 2] = b2;
  }
}

// ---------------- fused-MLP layer (R13 shape: 8-way o-split x 2 row-tiles) with
// TILE-MAJOR weights: af load = *(W + ((ot*NC + k)*64 + lane)*8) — one coalesced
// 1 KB wave transaction per fragment. wo in [0,8); guards fold except dh1/dh2 i=1.
template <int C, int O, int COFF, bool BN, bool RELU>
__device__ __forceinline__ void mlp_layer(const unsigned short* __restrict__ W,
                                          const float* __restrict__ bias,
                                          const float* __restrict__ bnp,
                                          const unsigned short* Xs,
                                          unsigned short* Ys,
                                          int wo, int q, int l15, int lane) {
  constexpr int NC = C / 32;
  constexpr int NT = O / 16;
  constexpr int MT = (NT + 7) / 8;
  f32x4 acc[MT][2];
  short8 afb[2][MT];
  const unsigned short* wp[MT];
#pragma unroll
  for (int i = 0; i < MT; ++i) {
    acc[i][0] = (f32x4){0.f, 0.f, 0.f, 0.f};
    acc[i][1] = (f32x4){0.f, 0.f, 0.f, 0.f};
    int ot = wo + i * 8;
    wp[i] = W + ((size_t)(((ot < NT) ? ot : 0) * NC) * 64 + lane) * 8;
  }
#pragma unroll
  for (int k = 0; k < 2 && k < NC; ++k)
#pragma unroll
    for (int i = 0; i < MT; ++i)
      if (wo + i * 8 < NT) afb[k][i] = *(const short8*)(wp[i] + (size_t)k * 512);
  short8 bf0 = *(const short8*)&Xs[l15 * 392 + q * 8];
  short8 bf1 = *(const short8*)&Xs[(16 + l15) * 392 + q * 8];
#pragma unroll
  for (int k = 0; k < NC; ++k) {
    short8 nbf0 = bf0, nbf1 = bf1;
    if (k + 1 < NC) {                  // compile-time
      nbf0 = *(const short8*)&Xs[l15 * 392 + (k + 1) * 32 + q * 8];
      nbf1 = *(const short8*)&Xs[(16 + l15) * 392 + (k + 1) * 32 + q * 8];
    }
    int slot = k & 1;
#pragma unroll
    for (int i = 0; i < MT; ++i) {
      if (wo + i * 8 < NT) {           // folds for all layers but dh1/dh2 i=1
        acc[i][0] = __builtin_amdgcn_mfma_f32_16x16x32_bf16(afb[slot][i], bf0, acc[i][0], 0, 0, 0);
        acc[i][1] = __builtin_amdgcn_mfma_f32_16x16x32_bf16(afb[slot][i], bf1, acc[i][1], 0, 0, 0);
      }
    }
    if (k + 2 < NC) {                  // compile-time
#pragma unroll
      for (int i = 0; i < MT; ++i)
        if (wo + i * 8 < NT) afb[slot][i] = *(const short8*)(wp[i] + (size_t)(k + 2) * 512);
    }
    bf0 = nbf0; bf1 = nbf1;
  }
#pragma unroll
  for (int i = 0; i < MT; ++i) {
    int ot = wo + i * 8;
    if (ot >= NT) continue;
    int o4 = ot * 16 + q * 4;
    f32x4 bb = *(const f32x4*)(bias + o4);
    f32x4 sc, sh;
    if (BN) {
      f32x4 g  = *(const f32x4*)(bnp + o4);
      f32x4 be = *(const f32x4*)(bnp + O + o4);
      f32x4 mm = *(const f32x4*)(bnp + 2 * O + o4);
      f32x4 vv = *(const f32x4*)(bnp + 3 * O + o4);
#pragma unroll
      for (int r = 0; r < 4; ++r) {
        float inv = g[r] * rsqrtf(vv[r] + 1e-5f);
        sc[r] = inv; sh[r] = (bb[r] - mm[r]) * inv + be[r];
      }
    } else {
      sc = (f32x4){1.f, 1.f, 1.f, 1.f}; sh = bb;
    }
#pragma unroll
    for (int rt = 0; rt < 2; ++rt) {
      ushort4 u;
#pragma unroll
      for (int r = 0; r < 4; ++r) {
        float x = acc[i][rt][r] * sc[r] + sh[r];
        if (RELU) x = fmaxf(x, 0.f);
        ((unsigned short*)&u)[r] = f2b(x);
      }
      *(ushort4*)&Ys[(rt * 16 + l15) * 392 + COFF + ot * 16 + q * 4] = u;
    }
  }
}

// ---------------- one-kernel MLP (R13 structure: 512 blocks x 32 rows)
__global__ __launch_bounds__(512) void k_mlp(
    const unsigned short* __restrict__ rgbTb,
    const float* __restrict__ pd, const int* __restrict__ pi,
    const unsigned short* __restrict__ fullp,
    const unsigned short* __restrict__ wcc1, const unsigned short* __restrict__ wcc2,
    const unsigned short* __restrict__ wco1, const unsigned short* __restrict__ wco2,
    const unsigned short* __restrict__ wdh1, const unsigned short* __restrict__ wdh2,
    const unsigned short* __restrict__ wdh3, const unsigned short* __restrict__ wsh1,
    const float* __restrict__ cc1_b, const float* __restrict__ cc_bn,
    const float* __restrict__ cc2_b,
    const float* __restrict__ co1_b, const float* __restrict__ co_bn,
    const float* __restrict__ co2_b,
    const float* __restrict__ dh1_b, const float* __restrict__ dh1_bn,
    const float* __restrict__ dh2_b, const float* __restrict__ dh2_bn,
    const float* __restrict__ dh3_b,
    const float* __restrict__ sh1_b, const float* __restrict__ sh_bn,
    const float* __restrict__ sh2_w, const float* __restrict__ sh2_b,
    const float* __restrict__ pxyz, float* __restrict__ out) {
  __shared__ unsigned short Ab[32 * 392];   // 24.5 KB
  __shared__ unsigned short Bb[32 * 392];   // 24.5 KB
  int t = threadIdx.x, lane = t & 63, w = t >> 6;
  int wo = w & 7;                           // range [0,8) for guard folding
  int q = lane >> 4, l15 = lane & 15;
  int n0 = blockIdx.x * 32;
  const float R2 = 0.075f * 0.075f;
  unsigned int mreg[4];                     // maxf held in registers
  // ---- merge (48-key lexicographic wave-min, verified) + gather + maxf
#pragma unroll
  for (int pj = 0; pj < 4; ++pj) {
    int r = w * 4 + pj;
    int n = n0 + r;
    int g = n >> 8, l = n & 255;
    unsigned long long key = ~0ull;
    if (lane < 48) {
      int s = lane / 3, qq = lane % 3;
      int off = ((g * 16 + s) * 256 + l) * 3 + qq;
      key = ((unsigned long long)__float_as_uint(pd[off]) << 32) | (unsigned int)pi[off];
    }
    unsigned long long mk[3];
#pragma unroll
    for (int rr = 0; rr < 3; ++rr) {
      unsigned long long m = key;
#pragma unroll
      for (int o = 1; o < 64; o <<= 1) {
        unsigned long long other = __shfl_xor(m, o);
        m = other < m ? other : m;
      }
      mk[rr] = m;
      if (key == m) key = ~0ull;
    }
    float d0 = __uint_as_float((unsigned int)(mk[0] >> 32));
    float d1 = __uint_as_float((unsigned int)(mk[1] >> 32));
    float d2 = __uint_as_float((unsigned int)(mk[2] >> 32));
    int j0 = (d0 > R2) ? NR : (int)(mk[0] & 0xffffffffu);
    int j1 = (d1 > R2) ? NR : (int)(mk[1] & 0xffffffffu);
    int j2 = (d2 > R2) ? NR : (int)(mk[2] & 0xffffffffu);
    unsigned int a = ((const unsigned int*)(rgbTb + (size_t)j0 * 128))[lane];
    unsigned int b = ((const unsigned int*)(rgbTb + (size_t)j1 * 128))[lane];
    unsigned int c = ((const unsigned int*)(rgbTb + (size_t)j2 * 128))[lane];
    unsigned int* xr = (unsigned int*)&Ab[r * 392];
    xr[lane] = a; xr[64 + lane] = b; xr[128 + lane] = c;
    float ml = fmaxf(blo(a), fmaxf(blo(b), blo(c)));
    float mh = fmaxf(bhi(a), fmaxf(bhi(b), bhi(c)));
    mreg[pj] = (__float_as_uint(mh) & 0xffff0000u) | (__float_as_uint(ml) >> 16);
  }
  __syncthreads();
  mlp_layer<384, 384, 0, true,  true >(wcc1, cc1_b, cc_bn, Ab, Bb, wo, q, l15, lane);
  __syncthreads();
  // cc2 writes Ab cols 0..127; maxf (registers) -> Ab cols 128..255 — disjoint.
#pragma unroll
  for (int pj = 0; pj < 4; ++pj)
    ((unsigned int*)&Ab[(w * 4 + pj) * 392])[64 + lane] = mreg[pj];
  mlp_layer<384, 128, 0, false, false>(wcc2, cc2_b, nullptr, Bb, Ab, wo, q, l15, lane);
  __syncthreads();
  mlp_layer<256, 256, 0, true,  true >(wco1, co1_b, co_bn, Ab, Bb, wo, q, l15, lane);
  __syncthreads();
  mlp_layer<256, 128, 32, false, false>(wco2, co2_b, nullptr, Bb, Ab, wo, q, l15, lane);
  for (int idx = t; idx < 128; idx += 512) {    // pcd feats -> Ab cols 0..31
    int row = idx >> 2, c8 = idx & 3;
    *(uint4*)&Ab[row * 392 + c8 * 8] = *(const uint4*)(fullp + (size_t)(n0 + row) * 32 + c8 * 8);
  }
  __syncthreads();
  mlp_layer<160, 160, 0, true,  true >(wdh1, dh1_b, dh1_bn, Ab, Bb, wo, q, l15, lane);
  __syncthreads();
  mlp_layer<160, 160, 0, true,  true >(wdh2, dh2_b, dh2_bn, Bb, Ab, wo, q, l15, lane);
  __syncthreads();
  mlp_layer<160, 128, 0, false, false>(wdh3, dh3_b, nullptr, Ab, Bb, wo, q, l15, lane); // fp -> Bb
  __syncthreads();
  mlp_layer<128, 128, 0, true,  true >(wsh1, sh1_b, sh_bn, Bb, Ab, wo, q, l15, lane);   // s  -> Ab
  __syncthreads();
  // ---- tail: wave w handles rows w*4 .. w*4+3 (score from Ab, norm from Bb)
  int col8 = (lane & 15) * 8;
  float4 w0 = *(const float4*)(sh2_w + col8);
  float4 wA = *(const float4*)(sh2_w + col8 + 4);
  float bvv = sh2_b[0];
  int row = w * 4 + (lane >> 4);
  uint4 raw = *(const uint4*)&Ab[row * 392 + col8];
  float acc = blo(raw.x) * w0.x + bhi(raw.x) * w0.y + blo(raw.y) * w0.z + bhi(raw.y) * w0.w +
              blo(raw.z) * wA.x + bhi(raw.z) * wA.y + blo(raw.w) * wA.z + bhi(raw.w) * wA.w;
  acc += __shfl_xor(acc, 1); acc += __shfl_xor(acc, 2);
  acc += __shfl_xor(acc, 4); acc += __shfl_xor(acc, 8);
  if ((lane & 15) == 0) out[49152 + n0 + row] = 1.f / (1.f + expf(-(acc + bvv)));
  uint4 rf = *(const uint4*)&Bb[row * 392 + col8];
  float v[8] = {blo(rf.x), bhi(rf.x), blo(rf.y), bhi(rf.y),
                blo(rf.z), bhi(rf.z), blo(rf.w), bhi(rf.w)};
  float s = 0.f;
#pragma unroll
  for (int i = 0; i < 8; ++i) s = fmaf(v[i], v[i], s);
  s += __shfl_xor(s, 1); s += __shfl_xor(s, 2);
  s += __shfl_xor(s, 4); s += __shfl_xor(s, 8);
  float inv = 1.f / fmaxf(sqrtf(s), 1e-12f);
  float* op = out + 65536 + (size_t)(n0 + row) * 128 + col8;
  *(float4*)op = make_float4(v[0] * inv, v[1] * inv, v[2] * inv, v[3] * inv);
  *(float4*)(op + 4) = make_float4(v[4] * inv, v[5] * inv, v[6] * inv, v[7] * inv);
  for (int i = t; i < 96; i += 512) out[n0 * 3 + i] = pxyz[n0 * 3 + i];
}

extern "C" void kernel_launch(void* const* d_in, const int* in_sizes, int n_in,
                              void* d_out, int out_size, void* d_ws, size_t ws_size,
                              hipStream_t stream) {
  const float* pcd_xyz = (const float*)d_in[0];
  const float* rgb_xyz = (const float*)d_in[1];
  const float* pcd_f   = (const float*)d_in[2];
  const float* rgb_f   = (const float*)d_in[3];
  const float* cc1_w = (const float*)d_in[4];  const float* cc1_b = (const float*)d_in[5];
  const float* cc_bn = (const float*)d_in[6];
  const float* cc2_w = (const float*)d_in[7];  const float* cc2_b = (const float*)d_in[8];
  const float* co1_w = (const float*)d_in[9];  const float* co1_b = (const float*)d_in[10];
  const float* co_bn = (const float*)d_in[11];
  const float* co2_w = (const float*)d_in[12]; const float* co2_b = (const float*)d_in[13];
  const float* dh1_w = (const float*)d_in[14]; const float* dh1_b = (const float*)d_in[15];
  const float* dh1_bn = (const float*)d_in[16];
  const float* dh2_w = (const float*)d_in[17]; const float* dh2_b = (const float*)d_in[18];
  const float* dh2_bn = (const float*)d_in[19];
  const float* dh3_w = (const float*)d_in[20]; const float* dh3_b = (const float*)d_in[21];
  const float* sh1_w = (const float*)d_in[22]; const float* sh1_b = (const float*)d_in[23];
  const float* sh_bn = (const float*)d_in[24];
  const float* sh2_w = (const float*)d_in[25]; const float* sh2_b = (const float*)d_in[26];

  char* ws = (char*)d_ws;
  float* out = (float*)d_out;

  unsigned short* wb    = (unsigned short*)(ws);              // 766 KB
  unsigned short* rgbTb = (unsigned short*)(ws + 0x100000);   // 2.1 MB
  float4* rxyz4         = (float4*)(ws + 0x320000);           // 128 KB
  float* pd  = (float*)(ws + 0x400000);                       // 3 MB
  int*   pi  = (int*)(ws + 0x700000);                         // 3 MB
  unsigned short* fullp = (unsigned short*)(ws + 0xA00000);   // (NP,32) bf16 = 1 MB

  unsigned short* wb_cc1 = wb;
  unsigned short* wb_cc2 = wb + 147456;
  unsigned short* wb_co1 = wb + 196608;
  unsigned short* wb_co2 = wb + 262144;
  unsigned short* wb_dh1 = wb + 294912;
  unsigned short* wb_dh2 = wb + 320512;
  unsigned short* wb_dh3 = wb + 346112;
  unsigned short* wb_sh1 = wb + 366592;

  k_pre<<<960, 256, 0, stream>>>(rgb_f, rgb_xyz, pcd_f,
                                 cc1_w, cc2_w, co1_w, co2_w, dh1_w, dh2_w, dh3_w, sh1_w,
                                 rgbTb, rxyz4, fullp, wb);
  k_nn_part<<<dim3(64, 16), 256, 0, stream>>>(pcd_xyz, rxyz4, pd, pi);
  k_mlp<<<512, 512, 0, stream>>>(rgbTb, pd, pi, fullp,
                                 wb_cc1, wb_cc2, wb_co1, wb_co2,
                                 wb_dh1, wb_dh2, wb_dh3, wb_sh1,
                                 cc1_b, cc_bn, cc2_b, co1_b, co_bn, co2_b,
                                 dh1_b, dh1_bn, dh2_b, dh2_bn, dh3_b,
                                 sh1_b, sh_bn, sh2_w, sh2_b,
                                 pcd_xyz, out);
}